// Round 8
// baseline (187.297 us; speedup 1.0000x reference)
//
#include <hip/hip_runtime.h>
#include <math.h>

#define NZ    128
#define H1    512
#define H2    1024
#define IMG   784
#define IMGP  832     // layer-3 N padded to 13*64
#define BATCH 4096
#define NGEN  10
#define MPAD  128     // packed-row slack so tail tiles can stage past ng

typedef _Float16 f16;
typedef __attribute__((ext_vector_type(8))) _Float16 half8;
typedef __attribute__((ext_vector_type(4))) float floatx4;

__device__ __forceinline__ void cp16(void* l, const void* g) {
    __builtin_amdgcn_global_load_lds((const __attribute__((address_space(1))) void*)g,
                                     (__attribute__((address_space(3))) void*)l, 16, 0, 0);
}

// ---------------- histogram + segment starts + permutation (one block) ----------------
__global__ __launch_bounds__(1024)
void hist_perm(const int* __restrict__ g_idx, int* __restrict__ seg,
               int* __restrict__ perm) {
    __shared__ int lc[NGEN];
    __shared__ int lb[NGEN + 1];
    const int t = threadIdx.x;
    if (t < NGEN) lc[t] = 0;
    __syncthreads();
    int gv[BATCH / 1024];
    #pragma unroll
    for (int i = 0; i < BATCH / 1024; ++i) {
        gv[i] = g_idx[t + i * 1024];
        atomicAdd(&lc[gv[i]], 1);
    }
    __syncthreads();
    if (t == 0) {
        int s = 0;
        for (int g = 0; g < NGEN; ++g) { lb[g] = s; s += lc[g]; }
        lb[NGEN] = s;
    }
    __syncthreads();
    if (t <= NGEN) seg[t] = lb[t];
    if (t < NGEN) lc[t] = lb[t];          // reuse as cursors
    __syncthreads();
    #pragma unroll
    for (int i = 0; i < BATCH / 1024; ++i) {
        int p = atomicAdd(&lc[gv[i]], 1);
        perm[p] = t + i * 1024;
    }
}

// ---------------- pack + convert z: zp[r][:] = f16(z[perm[r]][:]) ----------------
__global__ void pack_z(const float* __restrict__ z, const int* __restrict__ perm,
                       f16* __restrict__ zp) {
    const int i = blockIdx.x * 256 + threadIdx.x;   // BATCH * (NZ/4)
    const int r = i >> 5, c = (i & 31) * 4;
    const int s = perm[r];
    float4 v = *(const float4*)(z + (size_t)s * NZ + c);
    union { ushort4 u; f16 h[4]; } o;
    o.h[0] = (f16)v.x; o.h[1] = (f16)v.y; o.h[2] = (f16)v.z; o.h[3] = (f16)v.w;
    *(ushort4*)(zp + (size_t)r * NZ + c) = o.u;
}

// ---------------- transpose tile helper: [g][K][N] f32 -> [g][NPAD][K] f16 ----------------
template<int K, int N, int NPAD>
__device__ __forceinline__
void trans_tile(const float* __restrict__ W, f16* __restrict__ Wt,
                int kb, int nb, int g) {
    const int k0 = kb * 32, n0 = nb * 32;
    __shared__ f16 L[32][36];
    const int t = threadIdx.x;
    {
        const int kk = t >> 3;
        const int nq = (t & 7) * 4;
        float4 v = make_float4(0.f, 0.f, 0.f, 0.f);
        if (n0 + nq < N)   // N % 4 == 0: quads never straddle
            v = *(const float4*)(W + ((size_t)g * K + (k0 + kk)) * N + n0 + nq);
        L[nq + 0][kk] = (f16)v.x;
        L[nq + 1][kk] = (f16)v.y;
        L[nq + 2][kk] = (f16)v.z;
        L[nq + 3][kk] = (f16)v.w;
    }
    __syncthreads();
    {
        const int nn = t >> 3;
        const int kq = (t & 7) * 4;
        *(ushort4*)(Wt + ((size_t)g * NPAD + (n0 + nn)) * K + k0 + kq) =
            *(const ushort4*)&L[nn][kq];
    }
}

// one kernel for all three weight transposes (block-uniform branch)
#define T1 ((NZ / 32) * (H1 / 32))          // 64
#define T2 ((H1 / 32) * (H2 / 32))          // 512
#define T3 ((H2 / 32) * (IMGP / 32))        // 832
__global__ __launch_bounds__(256)
void transpose_all(const float* __restrict__ W1, const float* __restrict__ W2,
                   const float* __restrict__ W3, f16* __restrict__ W1t,
                   f16* __restrict__ W2t, f16* __restrict__ W3t) {
    const int g = blockIdx.z;
    const int x = blockIdx.x;
    if (x < T1) {
        trans_tile<NZ, H1, H1>(W1, W1t, x % (NZ / 32), x / (NZ / 32), g);
    } else if (x < T1 + T2) {
        const int t = x - T1;
        trans_tile<H1, H2, H2>(W2, W2t, t % (H1 / 32), t / (H1 / 32), g);
    } else {
        const int t = x - T1 - T2;
        trans_tile<H2, IMG, IMGP>(W3, W3t, t % (H2 / 32), t / (H2 / 32), g);
    }
}

// ---------------- 64x64-tile grouped GEMM, double-buffered async staging ----------------
// Block = (m-tile, n-tile, gen). global_load_lds width 16 into 2 LDS buffers.
// K-loop (AITER-style, vmcnt never 0):
//   barrier_A            -- all waves done READING buf[next] (no memory drain)
//   stage(kc+1)->buf[next]  (4 cp16/wave, stays IN FLIGHT across barriers)
//   s_waitcnt vmcnt(4)   -- drains only chunk kc's staging
//   barrier_B            -- chunk kc visible to all
//   compute(kc) from buf[kc&1]
// LDS XOR-swizzle: phys k-quad = logical ^ ((row>>1)&7) -> A-frag reads
// (consecutive rows) and col-permuted B-frag reads (stride-2 rows) both
// 2-way max (free). Column-permuted B: frag nf = memory col n0+wn+2*lm+nf ->
// lane accumulators are adjacent cols -> 2-elem vector stores.
// ACT: 0 relu, 1 tanh. SCATTER: 0 -> packed f16 Ch; 1 -> f32 out via perm.
template<int K, int NOUT, int NPADB, int ACT, int SCATTER>
__global__ __launch_bounds__(256)
void gemm64(const f16* __restrict__ Ap, const f16* __restrict__ Wt,
            const float* __restrict__ bias, f16* __restrict__ Ch,
            float* __restrict__ Cout, const int* __restrict__ seg,
            const int* __restrict__ perm) {
    constexpr int NI = K / 64;
    const int g  = blockIdx.z;
    const int s0 = seg[g];
    const int ng = seg[g + 1] - s0;
    const int m0 = blockIdx.x * 64;
    if (m0 >= ng) return;                 // block-uniform early exit
    const int n0 = blockIdx.y * 64;

    __shared__ f16 As[2][64 * 64];
    __shared__ f16 Bs[2][64 * 64];

    const int tid = threadIdx.x, lane = tid & 63, w = tid >> 6;

    // staging: wave w stages rows [w*16, w*16+16), 2 cp16 per matrix.
    // cp16 dest = wave-uniform base + lane*16 -> row = base + (lane>>3),
    // phys quad = lane&7; fetch global logical quad (lane&7) ^ ((row>>1)&7).
    const f16* ga[2]; const f16* gb[2]; int lofs[2];
    #pragma unroll
    for (int j = 0; j < 2; ++j) {
        const int r   = w * 16 + j * 8 + (lane >> 3);
        const int swz = ((lane & 7) ^ ((r >> 1) & 7)) * 8;
        ga[j] = Ap + (size_t)(s0 + m0 + r) * K + swz;
        gb[j] = Wt + ((size_t)g * NPADB + n0 + r) * K + swz;
        lofs[j] = (w * 16 + j * 8) * 64;
    }

    const int wm = (w & 1) * 32, wn = (w >> 1) * 32;
    const int lm = lane & 15, lq = lane >> 4;

    floatx4 acc[2][2] = {};

    // prologue: stage chunk 0 into buf 0
    #pragma unroll
    for (int j = 0; j < 2; ++j) {
        cp16(&As[0][lofs[j]], ga[j]); cp16(&Bs[0][lofs[j]], gb[j]);
    }

    #pragma unroll
    for (int kc = 0; kc < NI; ++kc) {
        __builtin_amdgcn_s_barrier();          // barrier_A: buf[next] read-free
        if (kc + 1 < NI) {
            const int nb = (kc + 1) & 1;
            #pragma unroll
            for (int j = 0; j < 2; ++j) {
                cp16(&As[nb][lofs[j]], ga[j] + (kc + 1) * 64);
                cp16(&Bs[nb][lofs[j]], gb[j] + (kc + 1) * 64);
            }
            __builtin_amdgcn_s_waitcnt(0x0F74);   // vmcnt(4): drain chunk kc only
        } else {
            __builtin_amdgcn_s_waitcnt(0x0F70);   // vmcnt(0): last chunk
        }
        __builtin_amdgcn_s_barrier();          // barrier_B: chunk kc published
        const f16* AsB = As[kc & 1];
        const f16* BsB = Bs[kc & 1];
        #pragma unroll
        for (int ks = 0; ks < 2; ++ks) {
            half8 a[2], b[2];
            #pragma unroll
            for (int mt = 0; mt < 2; ++mt) {
                const int r  = wm + mt * 16 + lm;
                const int pq = (ks * 4 + lq) ^ ((r >> 1) & 7);
                a[mt] = *(const half8*)&AsB[r * 64 + pq * 8];
            }
            #pragma unroll
            for (int nf = 0; nf < 2; ++nf) {
                const int r  = wn + 2 * lm + nf;
                const int pq = (ks * 4 + lq) ^ ((r >> 1) & 7);
                b[nf] = *(const half8*)&BsB[r * 64 + pq * 8];
            }
            #pragma unroll
            for (int mt = 0; mt < 2; ++mt)
                #pragma unroll
                for (int nf = 0; nf < 2; ++nf)
                    acc[mt][nf] = __builtin_amdgcn_mfma_f32_16x16x32_f16(
                        a[mt], b[nf], acc[mt][nf], 0, 0, 0);
        }
    }

    // epilogue: C/D layout col = lane&15 (-> memory col n0+wn+2*lm+nf),
    // row = (lane>>4)*4 + reg. Paired columns -> 2-elem vector stores.
    const int c = n0 + wn + 2 * lm;
    const float b0 = (c     < NOUT) ? bias[(size_t)g * NOUT + c]     : 0.f;
    const float b1 = (c + 1 < NOUT) ? bias[(size_t)g * NOUT + c + 1] : 0.f;
    #pragma unroll
    for (int mt = 0; mt < 2; ++mt)
        #pragma unroll
        for (int rr = 0; rr < 4; ++rr) {
            const int gr = m0 + wm + mt * 16 + lq * 4 + rr;
            if (gr >= ng) continue;
            float x0 = acc[mt][0][rr] + b0;
            float x1 = acc[mt][1][rr] + b1;
            if (ACT == 0) {
                x0 = fmaxf(x0, 0.f); x1 = fmaxf(x1, 0.f);
            } else {                       // tanh, inf-safe
                const float e0 = __expf(2.f * x0);
                const float e1 = __expf(2.f * x1);
                x0 = 1.f - 2.f / (e0 + 1.f);
                x1 = 1.f - 2.f / (e1 + 1.f);
            }
            if (SCATTER) {
                if (c < NOUT) {            // NOUT even: pair never straddles
                    const size_t orow = (size_t)perm[s0 + gr];
                    *(float2*)&Cout[orow * NOUT + c] = make_float2(x0, x1);
                }
            } else {
                union { uint u; f16 h[2]; } o;
                o.h[0] = (f16)x0; o.h[1] = (f16)x1;
                *(uint*)&Ch[(size_t)(s0 + gr) * NOUT + c] = o.u;
            }
        }
}

extern "C" void kernel_launch(void* const* d_in, const int* in_sizes, int n_in,
                              void* d_out, int out_size, void* d_ws, size_t ws_size,
                              hipStream_t stream) {
    const float* z    = (const float*)d_in[0];
    const int*   gidx = (const int*)  d_in[1];
    const float* W1   = (const float*)d_in[2];
    const float* b1   = (const float*)d_in[3];
    const float* W2   = (const float*)d_in[4];
    const float* b2   = (const float*)d_in[5];
    const float* W3   = (const float*)d_in[6];
    const float* b3   = (const float*)d_in[7];
    float* out = (float*)d_out;

    char* ws = (char*)d_ws;
    size_t off = 0;
    auto alloc = [&](size_t bytes) { size_t o = off; off = (off + bytes + 255) & ~255ULL; return o; };
    int* seg  = (int*)(ws + alloc((size_t)(NGEN + 1) * 4));
    int* perm = (int*)(ws + alloc((size_t)(BATCH + MPAD) * 4));
    f16* zp  = (f16*)(ws + alloc((size_t)(BATCH + MPAD) * NZ * 2));
    f16* h1p = (f16*)(ws + alloc((size_t)(BATCH + MPAD) * H1 * 2));
    f16* h2p = (f16*)(ws + alloc((size_t)(BATCH + MPAD) * H2 * 2));
    f16* W1t = (f16*)(ws + alloc((size_t)NGEN * H1 * NZ * 2));
    f16* W2t = (f16*)(ws + alloc((size_t)NGEN * H2 * H1 * 2));
    f16* W3t = (f16*)(ws + alloc((size_t)NGEN * IMGP * H2 * 2));

    hist_perm<<<dim3(1), dim3(1024), 0, stream>>>(gidx, seg, perm);
    pack_z<<<dim3(BATCH * (NZ / 4) / 256), dim3(256), 0, stream>>>(z, perm, zp);
    transpose_all<<<dim3(T1 + T2 + T3, 1, NGEN), dim3(256), 0, stream>>>(
        W1, W2, W3, W1t, W2t, W3t);

    // grid.x = 16 covers bucket sizes up to 1024; empty m-tiles exit early.
    gemm64<NZ, H1, H1, 0, 0><<<dim3(16, H1 / 64, NGEN), dim3(256), 0, stream>>>(
        zp, W1t, b1, h1p, nullptr, seg, perm);
    gemm64<H1, H2, H2, 0, 0><<<dim3(16, H2 / 64, NGEN), dim3(256), 0, stream>>>(
        h1p, W2t, b2, h2p, nullptr, seg, perm);
    gemm64<H2, IMG, IMGP, 1, 1><<<dim3(16, IMGP / 64, NGEN), dim3(256), 0, stream>>>(
        h2p, W3t, b3, nullptr, out, seg, perm);
}

// Round 9
// 182.113 us; speedup vs baseline: 1.0285x; 1.0285x over previous
//
#include <hip/hip_runtime.h>
#include <math.h>

#define NZ    128
#define H1    512
#define H2    1024
#define IMG   784
#define IMGP  832     // layer-3 N padded to 13*64
#define BATCH 4096
#define NGEN  10
#define MPAD  128     // packed-row slack so tail tiles can stage past ng

typedef _Float16 f16;
typedef __attribute__((ext_vector_type(8))) _Float16 half8;
typedef __attribute__((ext_vector_type(4))) float floatx4;

__device__ __forceinline__ void cp16(void* l, const void* g) {
    __builtin_amdgcn_global_load_lds((const __attribute__((address_space(1))) void*)g,
                                     (__attribute__((address_space(3))) void*)l, 16, 0, 0);
}

// ---------------- histogram + segment starts + permutation (one block) ----------------
__global__ __launch_bounds__(1024)
void hist_perm(const int* __restrict__ g_idx, int* __restrict__ seg,
               int* __restrict__ perm) {
    __shared__ int lc[NGEN];
    __shared__ int lb[NGEN + 1];
    const int t = threadIdx.x;
    if (t < NGEN) lc[t] = 0;
    __syncthreads();
    int gv[BATCH / 1024];
    #pragma unroll
    for (int i = 0; i < BATCH / 1024; ++i) {
        gv[i] = g_idx[t + i * 1024];
        atomicAdd(&lc[gv[i]], 1);
    }
    __syncthreads();
    if (t == 0) {
        int s = 0;
        for (int g = 0; g < NGEN; ++g) { lb[g] = s; s += lc[g]; }
        lb[NGEN] = s;
    }
    __syncthreads();
    if (t <= NGEN) seg[t] = lb[t];
    if (t < NGEN) lc[t] = lb[t];          // reuse as cursors
    __syncthreads();
    #pragma unroll
    for (int i = 0; i < BATCH / 1024; ++i) {
        int p = atomicAdd(&lc[gv[i]], 1);
        perm[p] = t + i * 1024;
    }
}

// ---------------- transpose tile helper: [g][K][N] f32 -> [g][NPAD][K] f16 ----------------
template<int K, int N, int NPAD>
__device__ __forceinline__
void trans_tile(const float* __restrict__ W, f16* __restrict__ Wt,
                int kb, int nb, int g) {
    const int k0 = kb * 32, n0 = nb * 32;
    __shared__ f16 L[32][36];
    const int t = threadIdx.x;
    {
        const int kk = t >> 3;
        const int nq = (t & 7) * 4;
        float4 v = make_float4(0.f, 0.f, 0.f, 0.f);
        if (n0 + nq < N)   // N % 4 == 0: quads never straddle
            v = *(const float4*)(W + ((size_t)g * K + (k0 + kk)) * N + n0 + nq);
        L[nq + 0][kk] = (f16)v.x;
        L[nq + 1][kk] = (f16)v.y;
        L[nq + 2][kk] = (f16)v.z;
        L[nq + 3][kk] = (f16)v.w;
    }
    __syncthreads();
    {
        const int nn = t >> 3;
        const int kq = (t & 7) * 4;
        *(ushort4*)(Wt + ((size_t)g * NPAD + (n0 + nn)) * K + k0 + kq) =
            *(const ushort4*)&L[nn][kq];
    }
}

// one prep kernel: all three weight transposes + z pack/convert (1D grid)
#define T1 ((NZ / 32) * (H1 / 32))          // 64
#define T2 ((H1 / 32) * (H2 / 32))          // 512
#define T3 ((H2 / 32) * (IMGP / 32))        // 832
#define TPG (T1 + T2 + T3)                  // 1408 transpose blocks per gen
#define PZB (BATCH * (NZ / 4) / 256)        // 512 pack blocks
__global__ __launch_bounds__(256)
void prep(const float* __restrict__ W1, const float* __restrict__ W2,
          const float* __restrict__ W3, f16* __restrict__ W1t,
          f16* __restrict__ W2t, f16* __restrict__ W3t,
          const float* __restrict__ z, const int* __restrict__ perm,
          f16* __restrict__ zp) {
    const int x = blockIdx.x;
    if (x < TPG * NGEN) {
        const int g = x / TPG, t = x % TPG;
        if (t < T1) {
            trans_tile<NZ, H1, H1>(W1, W1t, t % (NZ / 32), t / (NZ / 32), g);
        } else if (t < T1 + T2) {
            const int u = t - T1;
            trans_tile<H1, H2, H2>(W2, W2t, u % (H1 / 32), u / (H1 / 32), g);
        } else {
            const int u = t - T1 - T2;
            trans_tile<H2, IMG, IMGP>(W3, W3t, u % (H2 / 32), u / (H2 / 32), g);
        }
    } else {
        const int i = (x - TPG * NGEN) * 256 + threadIdx.x;  // BATCH*(NZ/4)
        const int r = i >> 5, c = (i & 31) * 4;
        const int s = perm[r];
        float4 v = *(const float4*)(z + (size_t)s * NZ + c);
        union { ushort4 u; f16 h[4]; } o;
        o.h[0] = (f16)v.x; o.h[1] = (f16)v.y; o.h[2] = (f16)v.z; o.h[3] = (f16)v.w;
        *(ushort4*)(zp + (size_t)r * NZ + c) = o.u;
    }
}

// ---------------- 64x64-tile grouped GEMM, single-buffer async staging ----------------
// Block = (m-tile, n-tile, gen). global_load_lds width 16; BK-chunk K-loop
// (BK=128 -> G1 stages its whole K in ONE chunk; G2 4 chunks; G3 8 chunks).
// LDS XOR-swizzle: phys 16B-quad = logical ^ ((row>>1)&7) -> A-frag reads
// (consecutive rows) and col-permuted B-frag reads (stride-2 rows) are both
// 2-way bank conflicts max (free per m136). Column-permuted B: frag nf holds
// memory col n0+wn+2*lm+nf -> lane accumulators are adjacent columns ->
// 2-elem vector stores (no partial-line RMW amplification).
// ACT: 0 relu, 1 tanh. SCATTER: 0 -> packed f16 Ch; 1 -> f32 out via perm.
template<int K, int BK, int NOUT, int NPADB, int ACT, int SCATTER>
__global__ __launch_bounds__(256)
void gemm64(const f16* __restrict__ Ap, const f16* __restrict__ Wt,
            const float* __restrict__ bias, f16* __restrict__ Ch,
            float* __restrict__ Cout, const int* __restrict__ seg,
            const int* __restrict__ perm) {
    constexpr int NI = K / BK;      // K-chunks
    constexpr int QR = BK / 8;      // 16B quads per LDS row
    constexpr int J  = QR / 4;      // cp16 per wave per matrix per chunk
    const int g  = blockIdx.z;
    const int s0 = seg[g];
    const int ng = seg[g + 1] - s0;
    const int m0 = blockIdx.x * 64;
    if (m0 >= ng) return;                 // block-uniform early exit
    const int n0 = blockIdx.y * 64;

    __shared__ f16 As[64 * BK];
    __shared__ f16 Bs[64 * BK];

    const int tid = threadIdx.x, lane = tid & 63, w = tid >> 6;

    // staging: wave w stages rows [w*16, w*16+16) of A and B. For cp16 j:
    // slot = j*64+lane -> row = w*16 + slot/QR, phys quad pq = slot%QR;
    // LDS dest = wave-uniform base + lane*16; fetch global logical quad
    // pq ^ ((row>>1)&7) so reads at phys (logical^swz) find the right data.
    const f16* ga[J]; const f16* gb[J]; int lofs[J];
    #pragma unroll
    for (int j = 0; j < J; ++j) {
        const int slot = j * 64 + lane;
        const int r    = w * 16 + slot / QR;
        const int pq   = slot % QR;
        const int src  = (pq ^ ((r >> 1) & 7)) * 8;
        ga[j] = Ap + (size_t)(s0 + m0 + r) * K + src;
        gb[j] = Wt + ((size_t)g * NPADB + n0 + r) * K + src;
        lofs[j] = (w * 16 * QR + j * 64 + lane) * 8;
    }

    const int wm = (w & 1) * 32, wn = (w >> 1) * 32;
    const int lm = lane & 15, lq = lane >> 4;

    floatx4 acc[2][2] = {};

    #pragma unroll
    for (int kc = 0; kc < NI; ++kc) {
        __syncthreads();                  // prior frag reads done: LDS reusable
        #pragma unroll
        for (int j = 0; j < J; ++j) {
            cp16(&As[lofs[j]], ga[j] + kc * BK);
            cp16(&Bs[lofs[j]], gb[j] + kc * BK);
        }
        __syncthreads();                  // staging drained (vmcnt before barrier)
        #pragma unroll
        for (int ks = 0; ks < BK / 32; ++ks) {
            half8 a[2], b[2];
            #pragma unroll
            for (int mt = 0; mt < 2; ++mt) {
                const int r  = wm + mt * 16 + lm;
                const int pq = (ks * 4 + lq) ^ ((r >> 1) & 7);
                a[mt] = *(const half8*)&As[r * BK + pq * 8];
            }
            #pragma unroll
            for (int nf = 0; nf < 2; ++nf) {
                const int r  = wn + 2 * lm + nf;
                const int pq = (ks * 4 + lq) ^ ((r >> 1) & 7);
                b[nf] = *(const half8*)&Bs[r * BK + pq * 8];
            }
            #pragma unroll
            for (int mt = 0; mt < 2; ++mt)
                #pragma unroll
                for (int nf = 0; nf < 2; ++nf)
                    acc[mt][nf] = __builtin_amdgcn_mfma_f32_16x16x32_f16(
                        a[mt], b[nf], acc[mt][nf], 0, 0, 0);
        }
    }

    // epilogue: C/D layout col = lane&15 (-> memory col n0+wn+2*lm+nf),
    // row = (lane>>4)*4 + reg. Paired columns -> 2-elem vector stores.
    const int c = n0 + wn + 2 * lm;
    const float b0 = (c     < NOUT) ? bias[(size_t)g * NOUT + c]     : 0.f;
    const float b1 = (c + 1 < NOUT) ? bias[(size_t)g * NOUT + c + 1] : 0.f;
    #pragma unroll
    for (int mt = 0; mt < 2; ++mt)
        #pragma unroll
        for (int rr = 0; rr < 4; ++rr) {
            const int gr = m0 + wm + mt * 16 + lq * 4 + rr;
            if (gr >= ng) continue;
            float x0 = acc[mt][0][rr] + b0;
            float x1 = acc[mt][1][rr] + b1;
            if (ACT == 0) {
                x0 = fmaxf(x0, 0.f); x1 = fmaxf(x1, 0.f);
            } else {                       // tanh, inf-safe
                const float e0 = __expf(2.f * x0);
                const float e1 = __expf(2.f * x1);
                x0 = 1.f - 2.f / (e0 + 1.f);
                x1 = 1.f - 2.f / (e1 + 1.f);
            }
            if (SCATTER) {
                if (c < NOUT) {            // NOUT even: pair never straddles
                    const size_t orow = (size_t)perm[s0 + gr];
                    *(float2*)&Cout[orow * NOUT + c] = make_float2(x0, x1);
                }
            } else {
                union { uint u; f16 h[2]; } o;
                o.h[0] = (f16)x0; o.h[1] = (f16)x1;
                *(uint*)&Ch[(size_t)(s0 + gr) * NOUT + c] = o.u;
            }
        }
}

extern "C" void kernel_launch(void* const* d_in, const int* in_sizes, int n_in,
                              void* d_out, int out_size, void* d_ws, size_t ws_size,
                              hipStream_t stream) {
    const float* z    = (const float*)d_in[0];
    const int*   gidx = (const int*)  d_in[1];
    const float* W1   = (const float*)d_in[2];
    const float* b1   = (const float*)d_in[3];
    const float* W2   = (const float*)d_in[4];
    const float* b2   = (const float*)d_in[5];
    const float* W3   = (const float*)d_in[6];
    const float* b3   = (const float*)d_in[7];
    float* out = (float*)d_out;

    char* ws = (char*)d_ws;
    size_t off = 0;
    auto alloc = [&](size_t bytes) { size_t o = off; off = (off + bytes + 255) & ~255ULL; return o; };
    int* seg  = (int*)(ws + alloc((size_t)(NGEN + 1) * 4));
    int* perm = (int*)(ws + alloc((size_t)(BATCH + MPAD) * 4));
    f16* zp  = (f16*)(ws + alloc((size_t)(BATCH + MPAD) * NZ * 2));
    f16* h1p = (f16*)(ws + alloc((size_t)(BATCH + MPAD) * H1 * 2));
    f16* h2p = (f16*)(ws + alloc((size_t)(BATCH + MPAD) * H2 * 2));
    f16* W1t = (f16*)(ws + alloc((size_t)NGEN * H1 * NZ * 2));
    f16* W2t = (f16*)(ws + alloc((size_t)NGEN * H2 * H1 * 2));
    f16* W3t = (f16*)(ws + alloc((size_t)NGEN * IMGP * H2 * 2));

    hist_perm<<<dim3(1), dim3(1024), 0, stream>>>(gidx, seg, perm);
    prep<<<dim3(TPG * NGEN + PZB), dim3(256), 0, stream>>>(
        W1, W2, W3, W1t, W2t, W3t, z, perm, zp);

    // grid.x = 16 covers bucket sizes up to 1024; empty m-tiles exit early.
    gemm64<NZ, 128, H1, H1, 0, 0><<<dim3(16, H1 / 64, NGEN), dim3(256), 0, stream>>>(
        zp, W1t, b1, h1p, nullptr, seg, perm);
    gemm64<H1, 128, H2, H2, 0, 0><<<dim3(16, H2 / 64, NGEN), dim3(256), 0, stream>>>(
        h1p, W2t, b2, h2p, nullptr, seg, perm);
    gemm64<H2, 128, IMG, IMGP, 1, 1><<<dim3(16, IMGP / 64, NGEN), dim3(256), 0, stream>>>(
        h2p, W3t, b3, nullptr, out, seg, perm);
}